// Round 1
// baseline (48760.812 us; speedup 1.0000x reference)
//
#include <hip/hip_runtime.h>

// STN-Euler LSTM scan. B=64, T=4096, IN=64, H=512, K=0.5.
// 256 persistent WGs: 4 batch-groups x 64 unit-slices. W slice in LDS (bf16),
// per-step h all-gather via device-scope atomics + monotone epoch flags.

#define Bsz  64
#define Tlen 4096
#define INs  64
#define Hs   512
#define KP   584          // padded LDS K stride: 512 + 64 + 8 (bank-conflict pad)
#define NG   4            // batch groups
#define GB   16           // batches per group (MFMA M=16)
#define RR   32           // gate rows per WG (8 units x 4 gates)

typedef float  floatx4 __attribute__((ext_vector_type(4)));
typedef short  short8  __attribute__((ext_vector_type(8)));

__device__ __forceinline__ unsigned short f2bf(float x) {
    unsigned u = __float_as_uint(x);
    u += 0x7fffu + ((u >> 16) & 1u);      // RNE
    return (unsigned short)(u >> 16);
}
__device__ __forceinline__ float sigmoidf_(float x) {
    return 1.0f / (1.0f + __expf(-x));
}
__device__ __forceinline__ float tanhf_(float x) {
    return 2.0f / (1.0f + __expf(-2.0f * x)) - 1.0f;   // inf-safe at both tails
}

__global__ __launch_bounds__(256, 2)
void stn_lstm_kernel(const float* __restrict__ x,
                     const float* __restrict__ W_ih,
                     const float* __restrict__ W_hh,
                     const float* __restrict__ b_ih,
                     const float* __restrict__ b_hh,
                     float* __restrict__ out,
                     unsigned* __restrict__ flags,   // [NG][64] monotone epochs
                     unsigned* __restrict__ hbuf)    // [2][NG][GB][256] u32 (2 bf16 each)
{
    __shared__ unsigned short Wlds[RR * KP];       // 37,376 B
    __shared__ unsigned short hx[GB * KP];         // 18,688 B  ([b][k] A-operand staging)
    __shared__ float gates_p[2][GB][RR];           //  4,096 B  (two K-half partials)
    __shared__ float biasL[RR];
    __shared__ unsigned short hpub[GB][8];         // h2 slice bf16 for packing

    const int tid = threadIdx.x;
    const int bid = blockIdx.x;
    const int g   = bid & 3;          // batch group
    const int u   = bid >> 2;         // unit slice 0..63 (units u*8 .. u*8+7)
    const int bg0 = g * GB;

    // ---- stage W_hh slice (local row r = gate*8 + j -> global row gate*512 + u*8 + j) ----
    for (int idx = tid; idx < RR * Hs / 4; idx += 256) {
        int r  = idx >> 7;
        int k4 = (idx & 127) * 4;
        int Rg = ((r >> 3) << 9) + u * 8 + (r & 7);
        const float4 v = *(const float4*)(W_hh + (size_t)Rg * Hs + k4);
        unsigned short* d = &Wlds[r * KP + k4];
        d[0] = f2bf(v.x); d[1] = f2bf(v.y); d[2] = f2bf(v.z); d[3] = f2bf(v.w);
    }
    // ---- stage W_ih slice into K range [512,576) ----
    for (int idx = tid; idx < RR * INs / 4; idx += 256) {
        int r  = idx >> 4;
        int k4 = (idx & 15) * 4;
        int Rg = ((r >> 3) << 9) + u * 8 + (r & 7);
        const float4 v = *(const float4*)(W_ih + (size_t)Rg * INs + k4);
        unsigned short* d = &Wlds[r * KP + Hs + k4];
        d[0] = f2bf(v.x); d[1] = f2bf(v.y); d[2] = f2bf(v.z); d[3] = f2bf(v.w);
    }
    if (tid < RR) {
        int Rg = ((tid >> 3) << 9) + u * 8 + (tid & 7);
        biasL[tid] = b_ih[Rg] + b_hh[Rg];
    }

    float c_state = 0.0f, h_state = 0.0f;     // fp32 recurrent state, tid<128 owns (b,j)
    const int eb = tid >> 3;                  // epilogue batch
    const int ej = tid & 7;                   // epilogue unit-in-slice

    const int lane = tid & 63;
    const int wv   = tid >> 6;
    const int nt   = wv >> 1;                 // n-tile (16 gate rows)
    const int kh   = wv & 1;                  // K half
    const int quad = lane >> 4;
    const int m16  = lane & 15;

    __syncthreads();

    for (int t = 0; t < Tlen; ++t) {
        // ---- phase A: obtain h^t into hx[b][0..511] ----
        if (t == 0) {
            #pragma unroll
            for (int q = 0; q < 8; ++q) {
                int idx = tid * 8 + q;            // 0..2047 u64 slots
                int b   = idx >> 7;
                int off = (idx & 127) * 4;
                *(unsigned long long*)&hx[b * KP + off] = 0ull;
            }
        } else {
            const unsigned target = (unsigned)t;
            while (true) {
                unsigned f = __hip_atomic_load(&flags[g * 64 + lane],
                                               __ATOMIC_RELAXED, __HIP_MEMORY_SCOPE_AGENT);
                // window test: poisoned 0xAAAAAAAA / stale values spin; producer lead <= 2
                if (__all((int)((f - target) < 16u))) break;
                __builtin_amdgcn_s_sleep(1);
            }
            const unsigned long long* src =
                (const unsigned long long*)hbuf + ((size_t)(t & 1) * NG + g) * (GB * 128);
            int b    = tid >> 4;
            int part = tid & 15;
            #pragma unroll
            for (int q = 0; q < 8; ++q) {
                int w = part * 8 + q;             // u64 index within batch row
                unsigned long long v = __hip_atomic_load(src + b * 128 + w,
                                          __ATOMIC_RELAXED, __HIP_MEMORY_SCOPE_AGENT);
                *(unsigned long long*)&hx[b * KP + w * 4] = v;
            }
        }
        // ---- phase B: x_t -> hx[b][512..575] ----
        {
            int b  = tid >> 4;
            int i4 = (tid & 15) * 4;
            const float4 v = *(const float4*)(x + ((size_t)(bg0 + b) * Tlen + t) * INs + i4);
            unsigned short* d = &hx[b * KP + Hs + i4];
            d[0] = f2bf(v.x); d[1] = f2bf(v.y); d[2] = f2bf(v.z); d[3] = f2bf(v.w);
        }
        __syncthreads();

        // ---- phase C: gates tile via MFMA (A: h/x, B: W slice) ----
        {
            floatx4 acc = {0.f, 0.f, 0.f, 0.f};
            const unsigned short* Ar = &hx[m16 * KP + quad * 8];
            const unsigned short* Br = &Wlds[(nt * 16 + m16) * KP + quad * 8];
            #pragma unroll
            for (int kt = 0; kt < 9; ++kt) {
                int k = (kh * 9 + kt) * 32;
                short8 af = *(const short8*)(Ar + k);
                short8 bf = *(const short8*)(Br + k);
                acc = __builtin_amdgcn_mfma_f32_16x16x32_bf16(af, bf, acc, 0, 0, 0);
            }
            #pragma unroll
            for (int r = 0; r < 4; ++r)
                gates_p[kh][quad * 4 + r][nt * 16 + m16] = acc[r];   // D: row=quad*4+r, col=lane&15
        }
        __syncthreads();

        // ---- phase D: pointwise LSTM + Euler blend (fp32 state in registers) ----
        if (tid < 128) {
            float gi = gates_p[0][eb][ej]      + gates_p[1][eb][ej]      + biasL[ej];
            float gf = gates_p[0][eb][8 + ej]  + gates_p[1][eb][8 + ej]  + biasL[8 + ej];
            float gg = gates_p[0][eb][16 + ej] + gates_p[1][eb][16 + ej] + biasL[16 + ej];
            float go = gates_p[0][eb][24 + ej] + gates_p[1][eb][24 + ej] + biasL[24 + ej];
            float ii = sigmoidf_(gi);
            float ff = sigmoidf_(gf);
            float gv = tanhf_(gg);
            float oo = sigmoidf_(go);
            float c_new = ff * c_state + ii * gv;
            float h_new = oo * tanhf_(c_new);
            float h2 = 0.5f * (h_state + h_new);     // K = 0.5
            float c2 = 0.5f * (c_state + c_new);
            h_state = h2; c_state = c2;
            out[((size_t)(bg0 + eb) * Tlen + t) * Hs + (u * 8 + ej)] = h2;
            hpub[eb][ej] = f2bf(h2);
        }
        __syncthreads();

        // ---- phase E: publish h2 slice + epoch flag (wave 0 only; release orders both) ----
        if (tid < 64) {
            int b  = tid >> 2;
            int jp = tid & 3;
            unsigned w32 = (unsigned)hpub[b][jp * 2] | ((unsigned)hpub[b][jp * 2 + 1] << 16);
            size_t o = (((size_t)((t + 1) & 1) * NG + g) * GB + b) * 256 + (size_t)u * 4 + jp;
            __hip_atomic_store(&hbuf[o], w32, __ATOMIC_RELAXED, __HIP_MEMORY_SCOPE_AGENT);
        }
        if (tid == 0) {
            __hip_atomic_store(&flags[g * 64 + u], (unsigned)(t + 1),
                               __ATOMIC_RELEASE, __HIP_MEMORY_SCOPE_AGENT);
        }
    }

    // ---- final [hT, cT] ----
    if (tid < 128) {
        size_t base = (size_t)Bsz * Tlen * Hs;
        int bgl = bg0 + eb;
        out[base + (size_t)bgl * 1024 + (u * 8 + ej)]       = h_state;
        out[base + (size_t)bgl * 1024 + 512 + (u * 8 + ej)] = c_state;
    }
}

extern "C" void kernel_launch(void* const* d_in, const int* in_sizes, int n_in,
                              void* d_out, int out_size, void* d_ws, size_t ws_size,
                              hipStream_t stream) {
    (void)in_sizes; (void)n_in; (void)out_size; (void)ws_size;
    const float* x    = (const float*)d_in[0];
    const float* W_ih = (const float*)d_in[1];
    const float* W_hh = (const float*)d_in[2];
    const float* b_ih = (const float*)d_in[3];
    const float* b_hh = (const float*)d_in[4];
    float* out = (float*)d_out;
    unsigned* flags = (unsigned*)d_ws;                     // 256 u32 (epoch-gated, poison-safe)
    unsigned* hbuf  = (unsigned*)((char*)d_ws + 1024);     // 2*4*16*256 u32 = 128 KB
    hipLaunchKernelGGL(stn_lstm_kernel, dim3(256), dim3(256), 0, stream,
                       x, W_ih, W_hh, b_ih, b_hh, out, flags, hbuf);
}

// Round 2
// 11627.048 us; speedup vs baseline: 4.1937x; 4.1937x over previous
//
#include <hip/hip_runtime.h>

// STN-Euler LSTM scan. B=64, T=4096, IN=64, H=512, K=0.5.
// 256 persistent WGs: 4 batch-groups x 64 unit-slices. W slice in LDS (bf16,
// XOR-swizzled 16B chunks), per-step h all-gather via LLC with one padded
// generation counter per group (no flags, no release fences).

#define Bsz  64
#define Tlen 4096
#define INs  64
#define Hs   512
#define NG   4            // batch groups
#define GB   16           // batches per group (MFMA M=16)
#define RR   32           // gate rows per WG (8 units x 4 gates)
#define NCH  72           // 16B chunks per K-row (576 bf16 / 8)

typedef float  floatx4 __attribute__((ext_vector_type(4)));
typedef short  short8  __attribute__((ext_vector_type(8)));

__device__ __forceinline__ unsigned short f2bf(float x) {
    unsigned u = __float_as_uint(x);
    u += 0x7fffu + ((u >> 16) & 1u);      // RNE
    return (unsigned short)(u >> 16);
}
__device__ __forceinline__ float sigmoidf_(float x) {
    return 1.0f / (1.0f + __expf(-x));
}
__device__ __forceinline__ float tanhf_(float x) {
    return 2.0f / (1.0f + __expf(-2.0f * x)) - 1.0f;   // inf-safe at both tails
}
// u16 index of 16B chunk c (0..71) of row b/r; XOR swizzle keeps all per-step
// LDS patterns <=2-way bank aliasing (free on CDNA4).
__device__ __forceinline__ int hx_idx(int b, int c) { return (b * NCH + (c ^ (b & 7))) * 8; }
__device__ __forceinline__ int w_idx (int r, int c) { return (r * NCH + (c ^ (r & 7))) * 8; }

__global__ __launch_bounds__(256, 2)
void stn_lstm_kernel(const float* __restrict__ x,
                     const float* __restrict__ W_ih,
                     const float* __restrict__ W_hh,
                     const float* __restrict__ b_ih,
                     const float* __restrict__ b_hh,
                     float* __restrict__ out,
                     unsigned* __restrict__ cnt,     // [NG] generation counters, 256B apart
                     unsigned* __restrict__ hbuf)    // [2][NG][64 prod][64 u32] payload
{
    __shared__ unsigned short Wlds[RR * NCH * 8];   // 36,864 B
    __shared__ unsigned short hx[GB * NCH * 8];     // 18,432 B
    __shared__ float gates_p[2][RR][17];            //  4,352 B ([kh][gaterow][batch+pad])
    __shared__ float biasL[RR];
    __shared__ unsigned short hpub[GB][8];

    const int tid = threadIdx.x;
    const int bid = blockIdx.x;
    const int g   = bid & 3;
    const int u   = bid >> 2;
    const int bg0 = g * GB;

    // ---- stage W_hh slice (local row r = gate*8+j -> global gate*512 + u*8 + j) ----
    for (int idx = tid; idx < RR * Hs / 4; idx += 256) {
        int r  = idx >> 7;
        int k4 = (idx & 127) * 4;
        int Rg = ((r >> 3) << 9) + u * 8 + (r & 7);
        const float4 v = *(const float4*)(W_hh + (size_t)Rg * Hs + k4);
        unsigned short* d = &Wlds[w_idx(r, k4 >> 3) + (k4 & 7)];
        d[0] = f2bf(v.x); d[1] = f2bf(v.y); d[2] = f2bf(v.z); d[3] = f2bf(v.w);
    }
    // ---- stage W_ih slice into chunks 64..71 ----
    for (int idx = tid; idx < RR * INs / 4; idx += 256) {
        int r  = idx >> 4;
        int k4 = (idx & 15) * 4;
        int Rg = ((r >> 3) << 9) + u * 8 + (r & 7);
        const float4 v = *(const float4*)(W_ih + (size_t)Rg * INs + k4);
        unsigned short* d = &Wlds[w_idx(r, 64 + (k4 >> 3)) + (k4 & 7)];
        d[0] = f2bf(v.x); d[1] = f2bf(v.y); d[2] = f2bf(v.z); d[3] = f2bf(v.w);
    }
    if (tid < RR) {
        int Rg = ((tid >> 3) << 9) + u * 8 + (tid & 7);
        biasL[tid] = b_ih[Rg] + b_hh[Rg];
    }

    float c_state = 0.0f, h_state = 0.0f;     // fp32 state, tid<128 owns (batch eb, unit ej)
    const int eb = tid >> 3;
    const int ej = tid & 7;

    const int lane = tid & 63;
    const int wv   = tid >> 6;
    const int nt   = wv >> 1;                 // n-tile (16 gate rows)
    const int kh   = wv & 1;                  // K half (9 chunks each)
    const int quad = lane >> 4;
    const int m16  = lane & 15;
    const int rr   = nt * 16 + m16;

    __syncthreads();

    for (int t = 0; t < Tlen; ++t) {
        // ---- x prefetch into registers (overlaps the poll) ----
        float4 xv0, xv1;
        if (tid < 128) {
            const float* xp = x + ((size_t)(bg0 + eb) * Tlen + t) * INs + ej * 8;
            xv0 = *(const float4*)xp;
            xv1 = *(const float4*)(xp + 4);
        }

        // ---- phase A: obtain h^t into hx chunks 0..63 ----
        if (t == 0) {
            int b = tid >> 4, part = tid & 15;
            #pragma unroll
            for (int q = 0; q < 8; ++q)               // zero h-part (u64 0..127 per row)
                ((unsigned long long*)hx)[b * 144 + part * 8 + q] = 0ull;
        } else {
            if (tid == 0) {
                const unsigned tgt = (unsigned)t << 6;
                while (__hip_atomic_load(&cnt[g * 64], __ATOMIC_RELAXED,
                                         __HIP_MEMORY_SCOPE_AGENT) < tgt)
                    __builtin_amdgcn_s_sleep(1);
            }
            __syncthreads();
            const unsigned long long* src = (const unsigned long long*)hbuf
                + ((size_t)(t & 1) * NG + g) * (64 * 32);
            const int b = tid & 15, u0 = tid >> 4;
            unsigned long long v[8];
            #pragma unroll
            for (int r = 0; r < 4; ++r) {
                int uu = u0 + 16 * r;
                v[2 * r]     = __hip_atomic_load(src + uu * 32 + b * 2,
                                   __ATOMIC_RELAXED, __HIP_MEMORY_SCOPE_SYSTEM);
                v[2 * r + 1] = __hip_atomic_load(src + uu * 32 + b * 2 + 1,
                                   __ATOMIC_RELAXED, __HIP_MEMORY_SCOPE_SYSTEM);
            }
            #pragma unroll
            for (int r = 0; r < 4; ++r) {
                int uu = u0 + 16 * r;
                *(unsigned long long*)&hx[hx_idx(b, uu)]     = v[2 * r];
                *(unsigned long long*)&hx[hx_idx(b, uu) + 4] = v[2 * r + 1];
            }
        }
        // ---- phase B: x -> hx chunks 64..71 ----
        if (tid < 128) {
            unsigned short* d = &hx[hx_idx(eb, 64 + ej)];
            d[0] = f2bf(xv0.x); d[1] = f2bf(xv0.y); d[2] = f2bf(xv0.z); d[3] = f2bf(xv0.w);
            d[4] = f2bf(xv1.x); d[5] = f2bf(xv1.y); d[6] = f2bf(xv1.z); d[7] = f2bf(xv1.w);
        }
        __syncthreads();

        // ---- phase C: gates tile via MFMA ----
        {
            floatx4 acc = {0.f, 0.f, 0.f, 0.f};
            #pragma unroll
            for (int kt = 0; kt < 9; ++kt) {
                int c = (kh * 9 + kt) * 4 + quad;
                short8 af = *(const short8*)&hx[hx_idx(m16, c)];
                short8 bf = *(const short8*)&Wlds[w_idx(rr, c)];
                acc = __builtin_amdgcn_mfma_f32_16x16x32_bf16(af, bf, acc, 0, 0, 0);
            }
            #pragma unroll
            for (int r2 = 0; r2 < 4; ++r2)
                gates_p[kh][rr][quad * 4 + r2] = acc[r2];   // D: row(batch)=quad*4+r2, col=m16
        }
        __syncthreads();

        // ---- phase D: pointwise LSTM + Euler blend ----
        if (tid < 128) {
            float gi = gates_p[0][ej][eb]      + gates_p[1][ej][eb]      + biasL[ej];
            float gf = gates_p[0][8 + ej][eb]  + gates_p[1][8 + ej][eb]  + biasL[8 + ej];
            float gg = gates_p[0][16 + ej][eb] + gates_p[1][16 + ej][eb] + biasL[16 + ej];
            float go = gates_p[0][24 + ej][eb] + gates_p[1][24 + ej][eb] + biasL[24 + ej];
            float ii = sigmoidf_(gi);
            float ff = sigmoidf_(gf);
            float gv = tanhf_(gg);
            float oo = sigmoidf_(go);
            float c_new = ff * c_state + ii * gv;
            float h_new = oo * tanhf_(c_new);
            float h2 = 0.5f * (h_state + h_new);     // K = 0.5
            float c2 = 0.5f * (c_state + c_new);
            h_state = h2; c_state = c2;
            __builtin_nontemporal_store(h2,
                &out[((size_t)(bg0 + eb) * Tlen + t) * Hs + (u * 8 + ej)]);
            hpub[eb][ej] = f2bf(h2);
        }
        __syncthreads();

        // ---- phase E: publish 256B payload (system-scope write-through), then count ----
        if (tid < 64) {
            int b = tid >> 2, jp = tid & 3;
            unsigned w32 = (unsigned)hpub[b][jp * 2] | ((unsigned)hpub[b][jp * 2 + 1] << 16);
            size_t o = (((size_t)((t + 1) & 1) * NG + g) * 64 + (size_t)u) * 64 + b * 4 + jp;
            __hip_atomic_store(&hbuf[o], w32, __ATOMIC_RELAXED, __HIP_MEMORY_SCOPE_SYSTEM);
        }
        __builtin_amdgcn_s_waitcnt(0x0f70);   // vmcnt(0): payload at LLC (syncthreads also drains)
        __syncthreads();
        if (tid == 0)
            __hip_atomic_fetch_add(&cnt[g * 64], 1u,
                                   __ATOMIC_RELAXED, __HIP_MEMORY_SCOPE_AGENT);
    }

    // ---- final [hT, cT] ----
    if (tid < 128) {
        size_t base = (size_t)Bsz * Tlen * Hs;
        int bgl = bg0 + eb;
        out[base + (size_t)bgl * 1024 + (u * 8 + ej)]       = h_state;
        out[base + (size_t)bgl * 1024 + 512 + (u * 8 + ej)] = c_state;
    }
}

extern "C" void kernel_launch(void* const* d_in, const int* in_sizes, int n_in,
                              void* d_out, int out_size, void* d_ws, size_t ws_size,
                              hipStream_t stream) {
    (void)in_sizes; (void)n_in; (void)out_size; (void)ws_size;
    const float* x    = (const float*)d_in[0];
    const float* W_ih = (const float*)d_in[1];
    const float* W_hh = (const float*)d_in[2];
    const float* b_ih = (const float*)d_in[3];
    const float* b_hh = (const float*)d_in[4];
    float* out = (float*)d_out;
    unsigned* cnt  = (unsigned*)d_ws;                   // 4 counters, 256B apart (zeroed below)
    unsigned* hbuf = (unsigned*)((char*)d_ws + 1024);   // 2*4*64*256 B = 128 KB payload
    hipMemsetAsync(d_ws, 0, 1024, stream);              // counters start at 0 every launch
    hipLaunchKernelGGL(stn_lstm_kernel, dim3(256), dim3(256), 0, stream,
                       x, W_ih, W_hh, b_ih, b_hh, out, cnt, hbuf);
}